// Round 3
// baseline (3011.179 us; speedup 1.0000x reference)
//
#include <hip/hip_runtime.h>

typedef __attribute__((ext_vector_type(8))) short short8;   // 8 bf16 = 4 VGPRs (MFMA A/B frag)
typedef __attribute__((ext_vector_type(4))) float f32x4;    // MFMA C/D frag
typedef __attribute__((ext_vector_type(4))) short short4v;

#define DM 768
#define DP 64

__device__ __forceinline__ unsigned short f2bf(float f) {
  unsigned u = __float_as_uint(f);
  u = u + 0x7fffu + ((u >> 16) & 1u);          // RNE
  return (unsigned short)(u >> 16);
}
__device__ __forceinline__ float bf2f(unsigned short s) {
  return __uint_as_float(((unsigned)s) << 16);
}
// mish(v) = v*tanh(softplus(v)) = v*(t^2+2t)/(t^2+2t+2), t=e^v (exact algebra, one exp)
__device__ __forceinline__ float mishf(float v) {
  float t = __expf(fminf(v, 30.0f));
  float num = t * (t + 2.0f);
  return v * (num / (num + 2.0f));
}

// Pre-pack weight [768,N] fp32 into MFMA B-fragment order, bf16:
//   dst[((kt*(N/16) + nt)*64 + lane)*8 + j] = bf16(src[(kt*32 + (lane>>4)*8 + j)*N + nt*16 + (lane&15)])
__global__ void cvt_frag(const float* __restrict__ src, unsigned short* __restrict__ dst,
                         int N, int ntPer) {
  constexpr int MAXC = 192;
  constexpr int TS = MAXC + 8;
  __shared__ unsigned short tile[32 * TS];
  const int kt = blockIdx.x;
  const int nt0 = blockIdx.y * ntPer;
  const int cols = ntPer * 16;
  for (int e = threadIdx.x; e < 32 * cols; e += blockDim.x) {
    int row = e / cols, col = e - row * cols;
    tile[row * TS + col] = f2bf(src[(kt * 32 + row) * N + nt0 * 16 + col]);
  }
  __syncthreads();
  const int NT = N / 16;
  for (int s = threadIdx.x; s < ntPer * 64; s += blockDim.x) {
    int ntl = s >> 6, l = s & 63;
    int m16 = l & 15, quad = l >> 4;
    short8 v;
    #pragma unroll
    for (int j = 0; j < 8; ++j)
      v[j] = (short)tile[(quad * 8 + j) * TS + ntl * 16 + m16];
    *(short8*)(dst + ((size_t)((kt * NT + nt0 + ntl) * 64 + l)) * 8) = v;
  }
}

// 2 blocks/CU: LDS = 81,920 B exactly (= 160 KiB / 2), VGPR forced <= 64 (8 waves/SIMD).
// Work split into two 32-row half-passes so h never needs more than 32x768 in LDS.
__global__ __launch_bounds__(1024, 8) void fused_policy(
    const float* __restrict__ x, const float* __restrict__ b1,
    const float* __restrict__ bq, const float* __restrict__ bk,
    const float* __restrict__ Wp, const float* __restrict__ bp,
    const int* __restrict__ idxs, int n_idx,
    const unsigned short* __restrict__ W1f,   // frag-packed [24][48][64][8]
    const unsigned short* __restrict__ Wqf,   // frag-packed [24][4][64][8]
    const unsigned short* __restrict__ Wkf,   // frag-packed [24][4][64][8]
    float* __restrict__ out) {
  constexpr int XS = 136;   // x chunk row stride (shorts): 32x128 bf16 +8 pad

  __shared__ __align__(16) unsigned char smem[81920];
  // Region A [0, 49152): xs0/xs1 (P1 K-loop) -> hs_half (P1 epi..P2) -> sc+promf (P3..P4)
  unsigned short* xs0 = (unsigned short*)smem;              // [0, 8704)
  unsigned short* xs1 = (unsigned short*)(smem + 8704);     // [8704, 17408)
  unsigned short* hs  = (unsigned short*)smem;              // 32x768 swizzled = 49152 B
  float* sc           = (float*)smem;                       // 64x64 f32 = 16384 B
  float* promf        = (float*)(smem + 16384);             // 128 B
  // Region B [49152, 81920): q/k hi+lo, stride 64 shorts, XOR-swizzled (no pad)
  unsigned short* qsh = (unsigned short*)(smem + 49152);
  unsigned short* qsl = (unsigned short*)(smem + 49152 + 8192);
  unsigned short* ksh = (unsigned short*)(smem + 49152 + 16384);
  unsigned short* ksl = (unsigned short*)(smem + 49152 + 24576);

  const int b    = blockIdx.x;
  const int tid  = threadIdx.x;
  const int wave = tid >> 6;
  const int lane = tid & 63;
  const int m16  = lane & 15;
  const int quad = lane >> 4;

  const float* xb = x + (size_t)b * (64 * DM);

  float b1v[3];
  #pragma unroll
  for (int ct = 0; ct < 3; ++ct) b1v[ct] = b1[wave * 48 + ct * 16 + m16];

  // per-wave W1 frag base: frag(kt,ct) = wb + kt*24576 + ct*512
  const unsigned short* wb = W1f + ((size_t)(wave * 3) * 64 + lane) * 8;

  // P2 wave roles (fixed across halves): waves 0-7 -> q, 8-15 -> k
  const int grp  = wave >> 3;
  const int w8   = wave & 7;
  const int rtl2 = w8 >> 2;              // local row tile 0..1
  const int ct2w = w8 & 3;               // output col tile 0..3
  const unsigned short* Wf = grp ? Wkf : Wqf;
  const float* bias2 = grp ? bk : bq;
  unsigned short* oh = grp ? ksh : qsh;
  unsigned short* ol = grp ? ksl : qsl;
  const unsigned short* wfb = Wf + ((size_t)ct2w * 64 + lane) * 8;   // + kt*2048

  // preload half0 chunk0 (1 float4 / thread = 32 rows x 128 cols)
  float4 pv = *(const float4*)(xb + (tid >> 5) * DM + (tid & 31) * 4);

  for (int half = 0; half < 2; ++half) {
    const float* xh = xb + half * 32 * DM;

    // ---------------- P1: h[32 rows] = mish(x@W1 + b1) -------------------------
    f32x4 acc[2][3];
    #pragma unroll
    for (int rtl = 0; rtl < 2; ++rtl)
      #pragma unroll
      for (int ct = 0; ct < 3; ++ct)
        #pragma unroll
        for (int r = 0; r < 4; ++r) acc[rtl][ct][r] = 0.0f;

    short8 bcur[3];
    #pragma unroll
    for (int ct = 0; ct < 3; ++ct) bcur[ct] = *(const short8*)(wb + ct * 512);

    for (int c = 0; c < 6; ++c) {
      unsigned short* xw = (c & 1) ? xs1 : xs0;
      {  // convert + store staged chunk
        short4v s4;
        s4.x = (short)f2bf(pv.x); s4.y = (short)f2bf(pv.y);
        s4.z = (short)f2bf(pv.z); s4.w = (short)f2bf(pv.w);
        *(short4v*)(xw + (tid >> 5) * XS + (tid & 31) * 4) = s4;
      }
      __syncthreads();
      if (c < 5)  // issue next chunk's HBM loads; drain behind this chunk's MFMAs
        pv = *(const float4*)(xh + (tid >> 5) * DM + (c + 1) * 128 + (tid & 31) * 4);
      #pragma unroll
      for (int ks = 0; ks < 4; ++ks) {
        const int kt = c * 4 + ks;
        short8 af0 = *(const short8*)(xw + m16 * XS + ks * 32 + quad * 8);
        short8 af1 = *(const short8*)(xw + (16 + m16) * XS + ks * 32 + quad * 8);
        #pragma unroll
        for (int ct = 0; ct < 3; ++ct) {
          short8 bn;
          if (kt < 23) bn = *(const short8*)(wb + (kt + 1) * 24576 + ct * 512);
          acc[0][ct] = __builtin_amdgcn_mfma_f32_16x16x32_bf16(af0, bcur[ct], acc[0][ct], 0, 0, 0);
          acc[1][ct] = __builtin_amdgcn_mfma_f32_16x16x32_bf16(af1, bcur[ct], acc[1][ct], 0, 0, 0);
          if (kt < 23) bcur[ct] = bn;
        }
      }
    }
    __syncthreads();   // xs region dead; hs (aliased) writes may begin

    if (half == 0)     // preload half1 chunk0 early: HBM latency hides under epi+P2
      pv = *(const float4*)(xb + 32 * DM + (tid >> 5) * DM + (tid & 31) * 4);

    // epilogue: bias + mish -> hs bf16, XOR-swizzled (granule=8 shorts, key=row&15)
    #pragma unroll
    for (int rtl = 0; rtl < 2; ++rtl)
      #pragma unroll
      for (int ct = 0; ct < 3; ++ct)
        #pragma unroll
        for (int r = 0; r < 4; ++r) {
          int row = rtl * 16 + quad * 4 + r;           // local 0..31
          int col = wave * 48 + ct * 16 + m16;
          hs[row * 768 + (col ^ ((row & 15) << 3))] = f2bf(mishf(acc[rtl][ct][r] + b1v[ct]));
        }
    __syncthreads();

    // ---------------- P2: q/k rows of this half; hi/lo bf16 split ---------------
    {
      f32x4 a2;
      #pragma unroll
      for (int r = 0; r < 4; ++r) a2[r] = 0.0f;

      const int arow = rtl2 * 16 + m16;                // local row 0..31, arow&15 == m16
      const unsigned short* hrow = hs + arow * 768;
      const int swz = m16 << 3;

      short8 a = *(const short8*)(hrow + ((quad * 8) ^ swz));
      short8 bf0 = *(const short8*)(wfb);
      for (int kt = 0; kt < 24; ++kt) {
        short8 an, bn;
        if (kt < 23) {
          an = *(const short8*)(hrow + (((kt + 1) * 32 + quad * 8) ^ swz));
          bn = *(const short8*)(wfb + (kt + 1) * 2048);
        }
        a2 = __builtin_amdgcn_mfma_f32_16x16x32_bf16(a, bf0, a2, 0, 0, 0);
        if (kt < 23) { a = an; bf0 = bn; }
      }
      #pragma unroll
      for (int r = 0; r < 4; ++r) {
        int rowg = half * 32 + rtl2 * 16 + quad * 4 + r;   // global 0..63
        int col = ct2w * 16 + m16;
        float v = a2[r] + bias2[col];
        unsigned short vh = f2bf(v);
        unsigned short vl = f2bf(v - bf2f(vh));
        int qi = rowg * 64 + (col ^ ((rowg & 7) << 3));    // 8-granule rows: key=row&7
        oh[qi] = vh; ol[qi] = vl;
      }
    }
    __syncthreads();   // qk written; hs dead -> next half may overwrite region A
  }

  // ---------------- P3: scores = q@k^T * 0.125 (16 tiles / 16 waves) -----------
  {
    const int rt = wave >> 2, ctt = wave & 3;
    f32x4 a3;
    #pragma unroll
    for (int r = 0; r < 4; ++r) a3[r] = 0.0f;
    const int qrow = rt * 16 + m16, krow = ctt * 16 + m16;
    const int sq = (qrow & 7) << 3, sk = (krow & 7) << 3;
    #pragma unroll
    for (int kt = 0; kt < 2; ++kt) {
      const int k0 = kt * 32 + quad * 8;
      short8 ah = *(const short8*)(qsh + qrow * 64 + (k0 ^ sq));
      short8 al = *(const short8*)(qsl + qrow * 64 + (k0 ^ sq));
      short8 bh = *(const short8*)(ksh + krow * 64 + (k0 ^ sk));
      short8 bl = *(const short8*)(ksl + krow * 64 + (k0 ^ sk));
      a3 = __builtin_amdgcn_mfma_f32_16x16x32_bf16(ah, bh, a3, 0, 0, 0);
      a3 = __builtin_amdgcn_mfma_f32_16x16x32_bf16(ah, bl, a3, 0, 0, 0);
      a3 = __builtin_amdgcn_mfma_f32_16x16x32_bf16(al, bh, a3, 0, 0, 0);
    }
    #pragma unroll
    for (int r = 0; r < 4; ++r)
      sc[(rt * 16 + quad * 4 + r) * 64 + ctt * 16 + m16] = a3[r] * 0.125f;

    if (wave == 15 && lane < 32) {
      // promf[rr*4+c] = bp[c] + sum_d k[56+rr][d] * Wp[d][c]
      const int rr = lane >> 2;
      const int c = lane & 3;
      float s = bp[c];
      const int krow2 = 56 + rr;                   // krow2&7 == rr
      const int swzk = rr << 3;
      #pragma unroll
      for (int d = 0; d < 64; ++d) {
        int ki = krow2 * 64 + (d ^ swzk);
        float kv = bf2f(ksh[ki]) + bf2f(ksl[ki]);
        s += kv * Wp[d * 4 + c];
      }
      promf[lane] = s;
    }
  }
  __syncthreads();

  // ---------------- P4: gather policy[:, indices] ------------------------------
  float* outb = out + (size_t)b * n_idx;
  for (int i = tid; i < n_idx; i += 1024) {
    int idx = idxs[i];
    float v;
    if (idx < 4096) {
      v = sc[idx];
    } else {
      int f = idx - 4096;        // flat index into promotion (8,24)==(3,64)
      int r = f / 24;
      int j = f - r * 24;
      int jj = j / 3;
      int cc = j - jj * 3;
      v = sc[(48 + r) * 64 + 56 + jj] + promf[jj * 4 + cc] + promf[jj * 4 + 3];
    }
    outb[i] = v;
  }
}

extern "C" void kernel_launch(void* const* d_in, const int* in_sizes, int n_in,
                              void* d_out, int out_size, void* d_ws, size_t ws_size,
                              hipStream_t stream) {
  const float* x  = (const float*)d_in[0];
  const float* W1 = (const float*)d_in[1];
  const float* b1 = (const float*)d_in[2];
  const float* Wq = (const float*)d_in[3];
  const float* bq = (const float*)d_in[4];
  const float* Wk = (const float*)d_in[5];
  const float* bk = (const float*)d_in[6];
  const float* Wp = (const float*)d_in[7];
  const float* bp = (const float*)d_in[8];
  const int* idxs = (const int*)d_in[9];

  const int B = in_sizes[0] / (64 * DM);   // 2048
  const int n_idx = in_sizes[9];           // 1858

  unsigned short* W1f = (unsigned short*)d_ws;        // [24][48][64][8] bf16 frags
  unsigned short* Wqf = W1f + 768 * 768;              // [24][4][64][8]
  unsigned short* Wkf = Wqf + 64 * 768;

  cvt_frag<<<dim3(24, 4), 256, 0, stream>>>(W1, W1f, 768, 12);
  cvt_frag<<<dim3(24, 1), 256, 0, stream>>>(Wq, Wqf, 64, 4);
  cvt_frag<<<dim3(24, 1), 256, 0, stream>>>(Wk, Wkf, 64, 4);

  fused_policy<<<B, 1024, 0, stream>>>(x, b1, bq, bk, Wp, bp, idxs, n_idx,
                                       W1f, Wqf, Wkf, (float*)d_out);
}

// Round 4
// 992.502 us; speedup vs baseline: 3.0339x; 3.0339x over previous
//
#include <hip/hip_runtime.h>

typedef __attribute__((ext_vector_type(8))) short short8;   // 8 bf16 = 4 VGPRs (MFMA A/B frag)
typedef __attribute__((ext_vector_type(4))) float f32x4;    // MFMA C/D frag
typedef __attribute__((ext_vector_type(4))) short short4v;

#define DM 768
#define DP 64

__device__ __forceinline__ unsigned short f2bf(float f) {
  unsigned u = __float_as_uint(f);
  u = u + 0x7fffu + ((u >> 16) & 1u);          // RNE
  return (unsigned short)(u >> 16);
}
__device__ __forceinline__ float bf2f(unsigned short s) {
  return __uint_as_float(((unsigned)s) << 16);
}
// mish(v) = v*tanh(softplus(v)) = v*(t^2+2t)/(t^2+2t+2), t=e^v (exact algebra, one exp)
__device__ __forceinline__ float mishf(float v) {
  float t = __expf(fminf(v, 30.0f));
  float num = t * (t + 2.0f);
  return v * (num / (num + 2.0f));
}

// Pre-pack weight [768,N] fp32 into MFMA B-fragment order, bf16:
//   dst[((kt*(N/16) + nt)*64 + lane)*8 + j] = bf16(src[(kt*32 + (lane>>4)*8 + j)*N + nt*16 + (lane&15)])
__global__ void cvt_frag(const float* __restrict__ src, unsigned short* __restrict__ dst,
                         int N, int ntPer) {
  constexpr int MAXC = 192;
  constexpr int TS = MAXC + 8;
  __shared__ unsigned short tile[32 * TS];
  const int kt = blockIdx.x;
  const int nt0 = blockIdx.y * ntPer;
  const int cols = ntPer * 16;
  for (int e = threadIdx.x; e < 32 * cols; e += blockDim.x) {
    int row = e / cols, col = e - row * cols;
    tile[row * TS + col] = f2bf(src[(kt * 32 + row) * N + nt0 * 16 + col]);
  }
  __syncthreads();
  const int NT = N / 16;
  for (int s = threadIdx.x; s < ntPer * 64; s += blockDim.x) {
    int ntl = s >> 6, l = s & 63;
    int m16 = l & 15, quad = l >> 4;
    short8 v;
    #pragma unroll
    for (int j = 0; j < 8; ++j)
      v[j] = (short)tile[(quad * 8 + j) * TS + ntl * 16 + m16];
    *(short8*)(dst + ((size_t)((kt * NT + nt0 + ntl) * 64 + l)) * 8) = v;
  }
}

// 768 threads (12 waves), 2 blocks/CU: LDS 81,920 B (= 160 KiB/2), VGPR budget
// 512/6 waves = ~80 -> low-pressure P1 (acc[2][4] + rotate-in-place b-prefetch).
__global__ __launch_bounds__(768, 6) void fused_policy(
    const float* __restrict__ x, const float* __restrict__ b1,
    const float* __restrict__ bq, const float* __restrict__ bk,
    const float* __restrict__ Wp, const float* __restrict__ bp,
    const int* __restrict__ idxs, int n_idx,
    const unsigned short* __restrict__ W1f,   // frag-packed [24][48][64][8]
    const unsigned short* __restrict__ Wqf,   // frag-packed [24][4][64][8] (follows W1f)
    const unsigned short* __restrict__ Wkf,   // frag-packed [24][4][64][8]
    float* __restrict__ out) {
  constexpr int XS = 104;   // x chunk row stride (shorts): 32x96 bf16 + 8 pad

  __shared__ __align__(16) unsigned char smem[81920];
  // Region A [0, 49152): xs0/xs1 (P1 K-loop) -> hs_half (P1 epi..P2) -> sc+promf (P3..P4)
  unsigned short* xs0 = (unsigned short*)smem;              // [0, 6656)
  unsigned short* xs1 = (unsigned short*)(smem + 6656);     // [6656, 13312)
  unsigned short* hs  = (unsigned short*)smem;              // 32x768 swizzled = 49152 B
  float* sc           = (float*)smem;                       // 64x64 f32 = 16384 B
  float* promf        = (float*)(smem + 16384);             // 128 B
  // Region B [49152, 81920): q/k hi+lo, stride 64 shorts, XOR-swizzled (no pad)
  unsigned short* qsh = (unsigned short*)(smem + 49152);
  unsigned short* qsl = (unsigned short*)(smem + 49152 + 8192);
  unsigned short* ksh = (unsigned short*)(smem + 49152 + 16384);
  unsigned short* ksl = (unsigned short*)(smem + 49152 + 24576);

  const int b    = blockIdx.x;
  const int tid  = threadIdx.x;
  const int wave = tid >> 6;       // 0..11
  const int lane = tid & 63;
  const int m16  = lane & 15;
  const int quad = lane >> 4;
  const int row24 = tid / 24;      // 0..31 (staging row)
  const int col24 = tid - row24 * 24;  // 0..23 (staging float4 col)

  const float* xb = x + (size_t)b * (64 * DM);

  // preload half0 chunk0: 32 rows x 96 f32 cols, exactly 1 float4/thread
  float4 pv = *(const float4*)(xb + row24 * DM + col24 * 4);

  for (int half = 0; half < 2; ++half) {
    const float* xh = xb + half * 32 * DM;

    // ---------------- P1: h[32 rows] = mish(x@W1 + b1) -------------------------
    // per wave: 32 rows x 64 cols (nt = wave*4 + ct, ct=0..3)
    f32x4 acc[2][4];
    #pragma unroll
    for (int rtl = 0; rtl < 2; ++rtl)
      #pragma unroll
      for (int ct = 0; ct < 4; ++ct)
        #pragma unroll
        for (int r = 0; r < 4; ++r) acc[rtl][ct][r] = 0.0f;

    // frag(kt, ct) = wbc + kt_in_chunk*24576 + ct*512 ; wbc advances 3 kt per chunk
    const unsigned short* wbc = W1f + ((size_t)(wave * 4) * 64 + lane) * 8;
    short8 bcur[4];
    #pragma unroll
    for (int ct = 0; ct < 4; ++ct) bcur[ct] = *(const short8*)(wbc + ct * 512);

    #pragma unroll 1
    for (int cc = 0; cc < 8; ++cc) {
      unsigned short* xw = (cc & 1) ? xs1 : xs0;
      {  // convert + store staged chunk (1 float4 -> 4 bf16 per thread)
        short4v s4;
        s4.x = (short)f2bf(pv.x); s4.y = (short)f2bf(pv.y);
        s4.z = (short)f2bf(pv.z); s4.w = (short)f2bf(pv.w);
        *(short4v*)(xw + row24 * XS + col24 * 4) = s4;
      }
      __syncthreads();
      if (cc < 7)  // issue next chunk's HBM loads; drain behind this chunk's MFMAs
        pv = *(const float4*)(xh + row24 * DM + (cc + 1) * 96 + col24 * 4);
      #pragma unroll
      for (int ks = 0; ks < 3; ++ks) {
        short8 af0 = *(const short8*)(xw + m16 * XS + ks * 32 + quad * 8);
        short8 af1 = *(const short8*)(xw + (16 + m16) * XS + ks * 32 + quad * 8);
        #pragma unroll
        for (int ct = 0; ct < 4; ++ct) {
          acc[0][ct] = __builtin_amdgcn_mfma_f32_16x16x32_bf16(af0, bcur[ct], acc[0][ct], 0, 0, 0);
          acc[1][ct] = __builtin_amdgcn_mfma_f32_16x16x32_bf16(af1, bcur[ct], acc[1][ct], 0, 0, 0);
          // rotate-in-place prefetch of frag(kt+1, ct); final one overruns into Wqf (safe, unused)
          bcur[ct] = *(const short8*)(wbc + (ks + 1) * 24576 + ct * 512);
        }
      }
      wbc += 3 * 24576;
    }
    __syncthreads();   // xs region dead; hs (aliased) writes may begin

    if (half == 0)     // preload half1 chunk0 early: HBM latency hides under epi+P2
      pv = *(const float4*)(xb + 32 * DM + row24 * DM + col24 * 4);

    // epilogue: bias + mish -> hs bf16, XOR-swizzled (granule=8 shorts, key=row&15)
    #pragma unroll
    for (int rtl = 0; rtl < 2; ++rtl)
      #pragma unroll
      for (int ct = 0; ct < 4; ++ct) {
        const float b1v = b1[wave * 64 + ct * 16 + m16];
        #pragma unroll
        for (int r = 0; r < 4; ++r) {
          int row = rtl * 16 + quad * 4 + r;           // local 0..31
          int col = wave * 64 + ct * 16 + m16;
          hs[row * 768 + (col ^ ((row & 15) << 3))] = f2bf(mishf(acc[rtl][ct][r] + b1v));
        }
      }
    __syncthreads();

    // ---------------- P2: q/k rows of this half; 16 tile-jobs on 12 waves ------
    for (int jj = wave; jj < 16; jj += 12) {
      const int grp = jj >> 3;               // 0=q, 1=k
      const int rt  = (jj >> 2) & 1;         // local row tile
      const int ct2 = jj & 3;                // output col tile
      const unsigned short* Wf = grp ? Wkf : Wqf;
      const float* bias2 = grp ? bk : bq;
      unsigned short* oh = grp ? ksh : qsh;
      unsigned short* ol = grp ? ksl : qsl;
      const unsigned short* wfb = Wf + ((size_t)ct2 * 64 + lane) * 8;   // + kt*2048

      f32x4 a2;
      #pragma unroll
      for (int r = 0; r < 4; ++r) a2[r] = 0.0f;

      const unsigned short* hrow = hs + (rt * 16 + m16) * 768;  // row&15 == m16
      const int swz = m16 << 3;

      short8 a = *(const short8*)(hrow + ((quad * 8) ^ swz));
      short8 bfr = *(const short8*)(wfb);
      for (int kt = 0; kt < 24; ++kt) {
        short8 an, bn;
        if (kt < 23) {
          an = *(const short8*)(hrow + (((kt + 1) * 32 + quad * 8) ^ swz));
          bn = *(const short8*)(wfb + (kt + 1) * 2048);
        }
        a2 = __builtin_amdgcn_mfma_f32_16x16x32_bf16(a, bfr, a2, 0, 0, 0);
        if (kt < 23) { a = an; bfr = bn; }
      }
      #pragma unroll
      for (int r = 0; r < 4; ++r) {
        int rowg = half * 32 + rt * 16 + quad * 4 + r;     // global 0..63
        int col = ct2 * 16 + m16;
        float v = a2[r] + bias2[col];
        unsigned short vh = f2bf(v);
        unsigned short vl = f2bf(v - bf2f(vh));
        int qi = rowg * 64 + (col ^ ((rowg & 7) << 3));    // 8-granule rows: key=row&7
        oh[qi] = vh; ol[qi] = vl;
      }
    }
    __syncthreads();   // qk written; hs dead -> next half may overwrite region A
  }

  // ---------------- P3: scores = q@k^T * 0.125 (16 tiles on 12 waves) ---------
  for (int t = wave; t < 16; t += 12) {
    const int rt = t >> 2, ctt = t & 3;
    f32x4 a3;
    #pragma unroll
    for (int r = 0; r < 4; ++r) a3[r] = 0.0f;
    const int qrow = rt * 16 + m16, krow = ctt * 16 + m16;
    const int sq = (qrow & 7) << 3, sk = (krow & 7) << 3;
    #pragma unroll
    for (int kt = 0; kt < 2; ++kt) {
      const int k0 = kt * 32 + quad * 8;
      short8 ah = *(const short8*)(qsh + qrow * 64 + (k0 ^ sq));
      short8 al = *(const short8*)(qsl + qrow * 64 + (k0 ^ sq));
      short8 bh = *(const short8*)(ksh + krow * 64 + (k0 ^ sk));
      short8 bl = *(const short8*)(ksl + krow * 64 + (k0 ^ sk));
      a3 = __builtin_amdgcn_mfma_f32_16x16x32_bf16(ah, bh, a3, 0, 0, 0);
      a3 = __builtin_amdgcn_mfma_f32_16x16x32_bf16(ah, bl, a3, 0, 0, 0);
      a3 = __builtin_amdgcn_mfma_f32_16x16x32_bf16(al, bh, a3, 0, 0, 0);
    }
    #pragma unroll
    for (int r = 0; r < 4; ++r)
      sc[(rt * 16 + quad * 4 + r) * 64 + ctt * 16 + m16] = a3[r] * 0.125f;
  }

  if (wave == 11 && lane < 32) {
    // promf[rr*4+c] = bp[c] + sum_d k[56+rr][d] * Wp[d][c]
    const int rr = lane >> 2;
    const int c = lane & 3;
    float s = bp[c];
    const int krow2 = 56 + rr;                   // krow2&7 == rr
    const int swzk = rr << 3;
    #pragma unroll
    for (int d = 0; d < 64; ++d) {
      int ki = krow2 * 64 + (d ^ swzk);
      float kv = bf2f(ksh[ki]) + bf2f(ksl[ki]);
      s += kv * Wp[d * 4 + c];
    }
    promf[lane] = s;
  }
  __syncthreads();

  // ---------------- P4: gather policy[:, indices] ------------------------------
  float* outb = out + (size_t)b * n_idx;
  for (int i = tid; i < n_idx; i += 768) {
    int idx = idxs[i];
    float v;
    if (idx < 4096) {
      v = sc[idx];
    } else {
      int f = idx - 4096;        // flat index into promotion (8,24)==(3,64)
      int r = f / 24;
      int j = f - r * 24;
      int jj = j / 3;
      int cc = j - jj * 3;
      v = sc[(48 + r) * 64 + 56 + jj] + promf[jj * 4 + cc] + promf[jj * 4 + 3];
    }
    outb[i] = v;
  }
}

extern "C" void kernel_launch(void* const* d_in, const int* in_sizes, int n_in,
                              void* d_out, int out_size, void* d_ws, size_t ws_size,
                              hipStream_t stream) {
  const float* x  = (const float*)d_in[0];
  const float* W1 = (const float*)d_in[1];
  const float* b1 = (const float*)d_in[2];
  const float* Wq = (const float*)d_in[3];
  const float* bq = (const float*)d_in[4];
  const float* Wk = (const float*)d_in[5];
  const float* bk = (const float*)d_in[6];
  const float* Wp = (const float*)d_in[7];
  const float* bp = (const float*)d_in[8];
  const int* idxs = (const int*)d_in[9];

  const int B = in_sizes[0] / (64 * DM);   // 2048
  const int n_idx = in_sizes[9];           // 1858

  unsigned short* W1f = (unsigned short*)d_ws;        // [24][48][64][8] bf16 frags
  unsigned short* Wqf = W1f + 768 * 768;              // [24][4][64][8] (contiguous after W1f)
  unsigned short* Wkf = Wqf + 64 * 768;

  cvt_frag<<<dim3(24, 4), 256, 0, stream>>>(W1, W1f, 768, 12);
  cvt_frag<<<dim3(24, 1), 256, 0, stream>>>(Wq, Wqf, 64, 4);
  cvt_frag<<<dim3(24, 1), 256, 0, stream>>>(Wk, Wkf, 64, 4);

  fused_policy<<<B, 768, 0, stream>>>(x, b1, bq, bk, Wp, bp, idxs, n_idx,
                                      W1f, Wqf, Wkf, (float*)d_out);
}